// Round 4
// baseline (23.691 us; speedup 1.0000x reference)
//
#include <hip/hip_runtime.h>
#include <cmath>

#define BSZ 32
#define NMEL 80
#define TMEL 800
#define NLAYERS 6
#define NHEADS 4
#define TTEXT 160
#define POS_WEIGHT 5.0f
#define GUIDE_K 3.125f

// block-role segmentation of a single fused kernel; 2048 blocks x 4 waves = full residency
// balanced by masked bytes: guide ~36.9MB, mel ~18.4MB -> 2:1
#define GUIDE_B 1360
#define MEL_B   680
#define GATE_B  8
#define TOTAL_B (GUIDE_B + MEL_B + GATE_B)   // 2048

// ws layout (floats)
#define WS_GUIDE 0
#define WS_MELA  (WS_GUIDE + GUIDE_B)
#define WS_MELB  (WS_MELA + MEL_B)
#define WS_GATE  (WS_MELB + MEL_B)

__device__ __forceinline__ float block_reduce_256(float v, float* lds) {
#pragma unroll
    for (int off = 32; off; off >>= 1) v += __shfl_xor(v, off, 64);
    if ((threadIdx.x & 63) == 0) lds[threadIdx.x >> 6] = v;
    __syncthreads();
    float r = 0.f;
    if (threadIdx.x == 0) r = lds[0] + lds[1] + lds[2] + lds[3];
    __syncthreads();
    return r;
}

__device__ __forceinline__ float softplus_f(float v) {
    return fmaxf(v, 0.f) + log1pf(expf(-fabsf(v)));
}

__global__ void fused_kernel(const float4* __restrict__ mo,
                             const float4* __restrict__ mop,
                             const float4* __restrict__ mt,
                             const float* __restrict__ A,
                             const float4* __restrict__ gx,
                             const float4* __restrict__ gy,
                             const int* __restrict__ mel_len,
                             const int* __restrict__ text_len,
                             float* __restrict__ ws) {
    __shared__ float lds[4];
    const int bid = blockIdx.x;

    if (bid < GUIDE_B) {
        // ---------------- guide loss (3 peeled iterations, loads hoisted) ----------------
        const int L4 = TTEXT / 4;                 // 40
        const int total = BSZ * TMEL * L4;        // 1,024,000 vec-items
        const int nthr = GUIDE_B * 256;           // 348,160
        const long long bstride = (long long)NLAYERS * NHEADS * TMEL * TTEXT;
        const long long lstride = (long long)NHEADS * TMEL * TTEXT;
        const long long hstride = (long long)TMEL * TTEXT;

        int   idxs[3];
        bool  valid[3];
        int   ts[3], tls[3], mls[3], l0s[3];
        float4 r[3][4];

        const int idx0 = bid * 256 + (int)threadIdx.x;
#pragma unroll
        for (int k = 0; k < 3; ++k) {
            int idx = idx0 + k * nthr;
            idxs[k] = idx;
            bool v = idx < total;
            int l4 = idx % L4;
            int t  = (idx / L4) % TMEL;
            int b  = idx / (L4 * TMEL);
            int ml = 0, tl = 0;
            if (v) { ml = mel_len[b]; tl = text_len[b]; }
            int l0 = l4 * 4;
            v = v && (t < ml) && (l0 < tl);
            valid[k] = v; ts[k] = t; tls[k] = tl; mls[k] = ml; l0s[k] = l0;
            if (v) {
                long long off = (long long)b * bstride + 4 * lstride +
                                (long long)t * TTEXT + l0;
                r[k][0] = *(const float4*)(A + off);
                r[k][1] = *(const float4*)(A + off + hstride);
                r[k][2] = *(const float4*)(A + off + lstride);
                r[k][3] = *(const float4*)(A + off + lstride + hstride);
            }
        }

        float s = 0.f;
#pragma unroll
        for (int k = 0; k < 3; ++k) {
            if (!valid[k]) continue;
            float inv_ml = __builtin_amdgcn_rcpf((float)mls[k]);
            float inv_tl = __builtin_amdgcn_rcpf((float)tls[k]);
            float tn = (float)ts[k] * inv_ml;
            float asum[4] = {r[k][0].x + r[k][1].x + r[k][2].x + r[k][3].x,
                             r[k][0].y + r[k][1].y + r[k][2].y + r[k][3].y,
                             r[k][0].z + r[k][1].z + r[k][2].z + r[k][3].z,
                             r[k][0].w + r[k][1].w + r[k][2].w + r[k][3].w};
#pragma unroll
            for (int j = 0; j < 4; ++j) {
                int l = l0s[k] + j;
                if (l < tls[k]) {
                    float d = tn - (float)l * inv_tl;
                    float w = 1.f - __expf(-GUIDE_K * d * d);
                    s += w * asum[j];
                }
            }
        }
        float rr = block_reduce_256(s, lds);
        if (threadIdx.x == 0) ws[WS_GUIDE + bid] = rr;

    } else if (bid < GUIDE_B + MEL_B) {
        // ---------------- mel L1 (3 peeled iterations, loads hoisted) ----------------
        const int mb = bid - GUIDE_B;
        const int T4 = TMEL / 4;                  // 200
        const int total = BSZ * NMEL * T4;        // 512,000 vec-items
        const int nthr = MEL_B * 256;             // 174,080

        bool  valid[3];
        int   t0s[3], mls[3];
        float4 a[3], p[3], g[3];

        const int idx0 = mb * 256 + (int)threadIdx.x;
#pragma unroll
        for (int k = 0; k < 3; ++k) {
            int idx = idx0 + k * nthr;
            bool v = idx < total;
            int t4 = idx % T4;
            int b  = idx / (NMEL * T4);
            int ml = 0;
            if (v) ml = mel_len[b];
            int t0 = t4 * 4;
            v = v && (t0 < ml);
            valid[k] = v; t0s[k] = t0; mls[k] = ml;
            if (v) {
                a[k] = mo[idx];
                p[k] = mop[idx];
                g[k] = mt[idx];
            }
        }

        float s_a = 0.f, s_b = 0.f;
#pragma unroll
        for (int k = 0; k < 3; ++k) {
            if (!valid[k]) continue;
            int ml = mls[k], t0 = t0s[k];
            float m0 = (t0 + 0 < ml) ? 1.f : 0.f;
            float m1 = (t0 + 1 < ml) ? 1.f : 0.f;
            float m2 = (t0 + 2 < ml) ? 1.f : 0.f;
            float m3 = (t0 + 3 < ml) ? 1.f : 0.f;
            s_a += fabsf(a[k].x - g[k].x) * m0 + fabsf(a[k].y - g[k].y) * m1 +
                   fabsf(a[k].z - g[k].z) * m2 + fabsf(a[k].w - g[k].w) * m3;
            s_b += fabsf(p[k].x - g[k].x) * m0 + fabsf(p[k].y - g[k].y) * m1 +
                   fabsf(p[k].z - g[k].z) * m2 + fabsf(p[k].w - g[k].w) * m3;
        }
        float ra = block_reduce_256(s_a, lds);
        float rb = block_reduce_256(s_b, lds);
        if (threadIdx.x == 0) {
            ws[WS_MELA + mb] = ra;
            ws[WS_MELB + mb] = rb;
        }
    } else {
        // ---------------- gate BCE ----------------
        const int gb = bid - GUIDE_B - MEL_B;
        const int T4 = TMEL / 4;                  // 200
        const int total = BSZ * T4;               // 6400 vec-items
        float s = 0.f;
        for (int idx = gb * 256 + threadIdx.x; idx < total; idx += GATE_B * 256) {
            int t4 = idx % T4;
            int b  = idx / T4;
            int ml = mel_len[b];
            int t0 = t4 * 4;
            if (t0 >= ml) continue;
            float4 xv = gx[idx];
            float4 yv = gy[idx];
            float e[4] = {
                POS_WEIGHT * yv.x * softplus_f(-xv.x) + (1.f - yv.x) * softplus_f(xv.x),
                POS_WEIGHT * yv.y * softplus_f(-xv.y) + (1.f - yv.y) * softplus_f(xv.y),
                POS_WEIGHT * yv.z * softplus_f(-xv.z) + (1.f - yv.z) * softplus_f(xv.z),
                POS_WEIGHT * yv.w * softplus_f(-xv.w) + (1.f - yv.w) * softplus_f(xv.w)};
#pragma unroll
            for (int j = 0; j < 4; ++j)
                if (t0 + j < ml) s += e[j];
        }
        float r = block_reduce_256(s, lds);
        if (threadIdx.x == 0) ws[WS_GATE + gb] = r;
    }
}

// ---------------- finalize: reduce partials + quotients ----------------
__global__ void finalize_kernel(const float* __restrict__ ws,
                                const int* __restrict__ mel_len,
                                const int* __restrict__ text_len,
                                float* __restrict__ out) {
    __shared__ float lds[4];
    float sg = 0.f, sa = 0.f, sb = 0.f, sgt = 0.f;
    for (int i = threadIdx.x; i < GUIDE_B; i += 256) sg += ws[WS_GUIDE + i];
    for (int i = threadIdx.x; i < MEL_B; i += 256) {
        sa += ws[WS_MELA + i];
        sb += ws[WS_MELB + i];
    }
    if (threadIdx.x < GATE_B) sgt = ws[WS_GATE + threadIdx.x];
    float rg  = block_reduce_256(sg, lds);
    float ra  = block_reduce_256(sa, lds);
    float rb  = block_reduce_256(sb, lds);
    float rgt = block_reduce_256(sgt, lds);
    if (threadIdx.x == 0) {
        double nv = 0.0, gsum = 0.0;
        for (int b = 0; b < BSZ; ++b) {
            int ml = min(mel_len[b], TMEL);
            int tl = min(text_len[b], TTEXT);
            nv += (double)ml;
            gsum += (double)ml * (double)tl;
        }
        double n_mel = nv * (double)NMEL;
        out[0] = (float)(((double)ra + (double)rb) / n_mel);
        out[1] = (float)((double)rgt / nv);
        out[2] = (float)((double)rg / (4.0 * gsum));
    }
}

extern "C" void kernel_launch(void* const* d_in, const int* in_sizes, int n_in,
                              void* d_out, int out_size, void* d_ws, size_t ws_size,
                              hipStream_t stream) {
    const float* mel_out      = (const float*)d_in[0];
    const float* mel_out_post = (const float*)d_in[1];
    const float* gate_out     = (const float*)d_in[2];
    const float* mel_target   = (const float*)d_in[3];
    const float* gate_target  = (const float*)d_in[4];
    const float* alignments   = (const float*)d_in[5];
    const int*   text_lengths = (const int*)d_in[6];
    const int*   mel_lengths  = (const int*)d_in[7];
    float* ws  = (float*)d_ws;
    float* out = (float*)d_out;

    fused_kernel<<<TOTAL_B, 256, 0, stream>>>((const float4*)mel_out,
                                              (const float4*)mel_out_post,
                                              (const float4*)mel_target,
                                              alignments,
                                              (const float4*)gate_out,
                                              (const float4*)gate_target,
                                              mel_lengths, text_lengths, ws);
    finalize_kernel<<<1, 256, 0, stream>>>(ws, mel_lengths, text_lengths, out);
}